// Round 18
// baseline (182.460 us; speedup 1.0000x reference)
//
#include <hip/hip_runtime.h>
#include <hip/hip_bf16.h>
#include <stdint.h>

#define NPTS 131072
#define DIM  512
#define KC   512
#define BM   128
#define BK   32
#define NKT  16          // DIM / BK

typedef float f32x16 __attribute__((ext_vector_type(16)));
typedef float f32x4  __attribute__((ext_vector_type(4)));
typedef short bf16x8 __attribute__((ext_vector_type(8)));

__device__ __forceinline__ float sq4(f32x4 a) {
  return a.x*a.x + a.y*a.y + a.z*a.z + a.w*a.w;
}

// packed RNE fp32->bf16 (v_cvt_pk_bf16_f32)
__device__ __forceinline__ bf16x8 pack8c(f32x4 a, f32x4 b) {
  union { __hip_bfloat162 h; short s[2]; } u0, u1, u2, u3;
  u0.h = __float22bfloat162_rn(make_float2(a.x, a.y));
  u1.h = __float22bfloat162_rn(make_float2(a.z, a.w));
  u2.h = __float22bfloat162_rn(make_float2(b.x, b.y));
  u3.h = __float22bfloat162_rn(make_float2(b.z, b.w));
  bf16x8 r;
  r[0] = u0.s[0]; r[1] = u0.s[1]; r[2] = u1.s[0]; r[3] = u1.s[1];
  r[4] = u2.s[0]; r[5] = u2.s[1]; r[6] = u3.s[0]; r[7] = u3.s[1];
  return r;
}

// scalar RNE (cluster pre-kernel only)
__device__ __forceinline__ short f2bf(float f) {
  union { float f; unsigned u; } v; v.f = f;
  unsigned r = v.u + 0x7FFFu + ((v.u >> 16) & 1u);
  return (short)(r >> 16);
}
__device__ __forceinline__ bf16x8 pack8(f32x4 a, f32x4 b) {
  bf16x8 p;
  p[0] = f2bf(a.x); p[1] = f2bf(a.y); p[2] = f2bf(a.z); p[3] = f2bf(a.w);
  p[4] = f2bf(b.x); p[5] = f2bf(b.y); p[6] = f2bf(b.z); p[7] = f2bf(b.w);
  return p;
}

__device__ __forceinline__ void gload_lds16(const void* g, void* l) {
  __builtin_amdgcn_global_load_lds(
      (const __attribute__((address_space(1))) unsigned int*)g,
      (__attribute__((address_space(3))) unsigned int*)l, 16, 0, 0);
}

// ---------------------------------------------------------------------------
// Cluster pre-kernel (layout verified R5-R17): fp32 [512][512] -> bf16 in
// MFMA-B-fragment order. Short offset = q*8192 + wn*2048 + nt*512 +
// (h*32+r)*8 where q = kt*2+st is the HALF-KT index — each 16 KB half-tile
// contiguous, staged linearly, fragments read at base + lane*16.
// c2[n] = ||c_n||^2 fp32.
// ---------------------------------------------------------------------------
__global__ void dec_pack(const float* __restrict__ C, short* __restrict__ Bp,
                         float* __restrict__ c2) {
  const int n    = blockIdx.x;
  const int lane = threadIdx.x;
  const float* src = C + (size_t)n * DIM + lane * 8;
  f32x4 v0 = *(const f32x4*)src;
  f32x4 v1 = *(const f32x4*)(src + 4);
  float s = sq4(v0) + sq4(v1);
  #pragma unroll
  for (int m = 1; m < 64; m <<= 1) s += __shfl_xor(s, m, 64);
  if (lane == 0) c2[n] = s;
  const int kt = lane >> 2;
  const int st = (lane >> 1) & 1;
  const int hh = lane & 1;
  const int wn = n >> 7, nt = (n >> 5) & 3, r = n & 31;
  const size_t slot =
      (((size_t)(kt * 2 + st) * 4 + wn) * 4 + nt) * 64 + hh * 32 + r;
  *(bf16x8*)(Bp + slot * 8) = pack8(v0, v1);
}

// ---------------------------------------------------------------------------
// Main fused kernel (R18): BM=128, 1024 threads = 16 waves, halved B
// re-staging (2 MB/CU vs R11's 4), counted-vmcnt phase schedule.
// Waves: wm = wave>>2 (0..3) x wn = wave&3; wave tile 32 x 128
// (acc = 4 x f32x16 = 64 AGPR, ~124 unified regs -> 4 waves/SIMD,
// all 16 waves of the single block resident).
//
// 32 phases (2 per BK=32 kt). Phase bodies:
//   even p=2kt: [vmcnt(1); s_barrier] [stage B-half(2kt+2) 1 op/thread +
//               A(kt+1) 1 op/thread] [compute kt s=0]
//   odd p=2kt+1: [vmcnt(2); s_barrier] [stage B-half(2kt+3) 1 op/thread]
//               [compute kt s=1]
// Waits keep the previous phase's ops in flight; every buffer waited on is
// one full phase old. All staging ops are uniform across waves (1024
// threads x 16 B = exactly one 16 KB tile per op-group).
// A: dest linear t*16B (lane*16 contract); source chunk (t&7)^(row&7) —
//   the R13-proven full-bank-wrap XOR (rows stride 128 B); read at
//   chunk (s*4+h*2+i)^(row&7) — conflict-free.
// B: ring-3 16 KB halves, fragments read linear at base + lane*16.
// LDS: 48 KB B-ring + 32 KB A-dbuf = 80 KB -> 1 block/CU (16 waves, 50%).
// Staged bytes/CU: B 4 x 512 KB = 2 MB + A 1 MB = 3 MB (R11: 5 MB).
// ---------------------------------------------------------------------------
__global__ __launch_bounds__(1024, 4)
void dec_main(const float* __restrict__ X, const short* __restrict__ Bp,
              const float* __restrict__ c2g, float* __restrict__ out) {
  __shared__ short Bh[3][8192];     // 3 x 16 KB half-kt B tiles
  __shared__ float Ab[2][4096];     // 2 x 16 KB fp32 A tiles (swizzled chunks)

  const int tid  = threadIdx.x;
  const int lane = tid & 63;
  const int wave = tid >> 6;
  const int wm   = wave >> 2;   // 0..3 : row quarter (32 rows each)
  const int wn   = wave & 3;    // 0..3 : column quarter
  const int l31  = lane & 31;
  const int h    = lane >> 5;
  const int row0 = blockIdx.x * BM;

  // A staging: thread t -> row t>>3 (0..127), dest chunk t&7 at linear
  // t*16B; source chunk (t&7)^(row&7) (full-bank-wrap XOR, R13-proven).
  const float* asrc = X + (size_t)(row0 + (tid >> 3)) * DIM +
                      (((tid & 7) ^ ((tid >> 3) & 7)) << 2);
  // B staging: one 16B op per thread per half-tile, linear
  const short* bsrc = Bp + tid * 8;

  // A fragment read base (floats): row (wm*32+l31), stride 32 floats
  const int abase = (wm * 32 + l31) * BK;
  const int asw   = l31 & 7;    // read-side XOR ((wm*32+l31)&7 == l31&7)

  f32x16 acc[4];
  #pragma unroll
  for (int nt = 0; nt < 4; ++nt) acc[nt] = (f32x16)0.f;
  float x2 = 0.f;

  // ---- prologue: A(0), B-half(0), B-half(1)  (3 ops/thread) ----
  gload_lds16(asrc, &Ab[0][tid * 4]);
  gload_lds16(bsrc, &Bh[0][tid * 8]);
  __builtin_amdgcn_sched_barrier(0);
  gload_lds16(bsrc + 8192, &Bh[1][tid * 8]);
  __builtin_amdgcn_sched_barrier(0);

  for (int kt = 0; kt < NKT; ++kt) {
    const int rb  = (2 * kt) % 3;         // slot of (kt, s=0)
    const int rb1 = (2 * kt + 1) % 3;     // slot of (kt, s=1)
    const int rb2 = (2 * kt + 2) % 3;     // stage target (even phase)
    const int rb3 = (2 * kt + 3) % 3;     // stage target (odd phase)

    // ================= even phase p = 2kt =================
    asm volatile("s_waitcnt vmcnt(1)" ::: "memory");
    __builtin_amdgcn_sched_barrier(0);
    __builtin_amdgcn_s_barrier();
    __builtin_amdgcn_sched_barrier(0);
    {
      const int q  = (2 * kt + 2 < 32) ? 2 * kt + 2 : 31;   // B half index
      const int ka = (kt + 1 < NKT) ? kt + 1 : NKT - 1;     // A tile index
      gload_lds16(bsrc + (size_t)q * 8192, &Bh[rb2][tid * 8]);
      gload_lds16(asrc + ka * BK, &Ab[(kt + 1) & 1][tid * 4]);
    }
    __builtin_amdgcn_sched_barrier(0);
    {
      const float* A = &Ab[kt & 1][0];
      f32x4 lo = *(const f32x4*)&A[abase + (((h * 2 + 0) ^ asw) << 2)];
      f32x4 hi = *(const f32x4*)&A[abase + (((h * 2 + 1) ^ asw) << 2)];
      x2 += sq4(lo) + sq4(hi);
      bf16x8 af = pack8c(lo, hi);
      bf16x8 bfr[4];
      #pragma unroll
      for (int nt = 0; nt < 4; ++nt)
        bfr[nt] = *(const bf16x8*)&Bh[rb][(wn * 4 + nt) * 512 + lane * 8];
      #pragma unroll
      for (int nt = 0; nt < 4; ++nt)
        acc[nt] = __builtin_amdgcn_mfma_f32_32x32x16_bf16(
            af, bfr[nt], acc[nt], 0, 0, 0);
    }

    // ================= odd phase p = 2kt+1 =================
    asm volatile("s_waitcnt vmcnt(2)" ::: "memory");
    __builtin_amdgcn_sched_barrier(0);
    __builtin_amdgcn_s_barrier();
    __builtin_amdgcn_sched_barrier(0);
    {
      const int q = (2 * kt + 3 < 32) ? 2 * kt + 3 : 31;
      gload_lds16(bsrc + (size_t)q * 8192, &Bh[rb3][tid * 8]);
    }
    __builtin_amdgcn_sched_barrier(0);
    {
      const float* A = &Ab[kt & 1][0];
      f32x4 lo = *(const f32x4*)&A[abase + (((4 + h * 2 + 0) ^ asw) << 2)];
      f32x4 hi = *(const f32x4*)&A[abase + (((4 + h * 2 + 1) ^ asw) << 2)];
      x2 += sq4(lo) + sq4(hi);
      bf16x8 af = pack8c(lo, hi);
      bf16x8 bfr[4];
      #pragma unroll
      for (int nt = 0; nt < 4; ++nt)
        bfr[nt] = *(const bf16x8*)&Bh[rb1][(wn * 4 + nt) * 512 + lane * 8];
      #pragma unroll
      for (int nt = 0; nt < 4; ++nt)
        acc[nt] = __builtin_amdgcn_mfma_f32_32x32x16_bf16(
            af, bfr[nt], acc[nt], 0, 0, 0);
    }
  }

  // drain dead tail stages before overlaying epilogue scratch on Ab
  __syncthreads();

  // ---- x2: combine the two k-halves; lane l31 holds x2(row wm*32+l31) ----
  x2 += __shfl_xor(x2, 32, 64);

  float c2v[4];
  #pragma unroll
  for (int nt = 0; nt < 4; ++nt) c2v[nt] = c2g[wn * 128 + nt * 32 + l31];

  // ---- q = rcp(1+d2), per-row partial sums over this wave's 128 cols ----
  float srow[16];
  #pragma unroll
  for (int r = 0; r < 16; ++r) {
    const int mloc = (r & 3) + 8 * (r >> 2) + 4 * h;   // 0..31
    const float x2m = __shfl(x2, mloc, 64);
    float s = 0.f;
    #pragma unroll
    for (int nt = 0; nt < 4; ++nt) {
      float d2 = fmaxf(x2m + c2v[nt] - 2.f * acc[nt][r], 0.f);
      float q = __builtin_amdgcn_rcpf(1.f + d2);
      acc[nt][r] = q;
      s += q;
    }
    #pragma unroll
    for (int msk = 1; msk < 32; msk <<= 1) s += __shfl_xor(s, msk, 64);
    srow[r] = s;
  }

  // epilogue scratch overlaid on Ab (dead after the drain barrier)
  float* part   = &Ab[0][0];        // [4][BM]
  float* rowinv = &Ab[0][4 * BM];

  if (l31 == 0) {
    #pragma unroll
    for (int r = 0; r < 16; ++r)
      part[wn * BM + wm * 32 + (r & 3) + 8 * (r >> 2) + 4 * h] = srow[r];
  }
  __syncthreads();
  if (tid < BM)
    rowinv[tid] = __builtin_amdgcn_rcpf(part[tid] + part[BM + tid] +
                                        part[2 * BM + tid] + part[3 * BM + tid]);
  __syncthreads();

  // ---- normalize + coalesced stores ----
  #pragma unroll
  for (int r = 0; r < 16; ++r) {
    const int row = wm * 32 + (r & 3) + 8 * (r >> 2) + 4 * h;
    const float iv = rowinv[row];
    float* o = out + (size_t)(row0 + row) * KC + wn * 128 + l31;
    #pragma unroll
    for (int nt = 0; nt < 4; ++nt)
      o[nt * 32] = acc[nt][r] * iv;
  }
}

extern "C" void kernel_launch(void* const* d_in, const int* in_sizes, int n_in,
                              void* d_out, int out_size, void* d_ws, size_t ws_size,
                              hipStream_t stream) {
  const float* X = (const float*)d_in[0];   // inputs  [131072, 512] fp32
  const float* C = (const float*)d_in[1];   // clusters [512, 512] fp32
  float* out = (float*)d_out;               // [131072, 512] fp32

  short* Bp = (short*)d_ws;                                   // 512 KB packed bf16 clusters
  float* c2 = (float*)((char*)d_ws + (size_t)KC * DIM * 2);   // 2 KB cluster norms

  dec_pack<<<KC, 64, 0, stream>>>(C, Bp, c2);
  dec_main<<<NPTS / BM, 1024, 0, stream>>>(X, Bp, c2, out);
}